// Round 1
// baseline (799.252 us; speedup 1.0000x reference)
//
#include <hip/hip_runtime.h>
#include <hip/hip_bf16.h>
#include <cstdint>
#include <cstddef>

typedef unsigned short u16;
typedef __attribute__((ext_vector_type(8))) short short8;   // 8 x bf16 (4 VGPRs) MFMA frag
typedef __attribute__((ext_vector_type(4))) float f32x4;    // MFMA accum

#define D_MODEL 2048
#define SEQ     2048
#define BATCH   4
#define NHEADS  16
#define DKH     128
#define NTOK    (BATCH*SEQ)   // 8192

__device__ inline float bf2f(u16 u) {
  union { float f; unsigned int i; } x; x.i = ((unsigned int)u) << 16; return x.f;
}
__device__ inline u16 f2bf(float f) {
  union { float f; unsigned int i; } x; x.f = f;
  return (u16)((x.i + 0x7FFFu + ((x.i >> 16) & 1u)) >> 16);   // RNE
}

// ---------------- fp32 -> bf16 convert, 8 elems/thread ----------------
__global__ void cvt_kernel(const float* __restrict__ in, u16* __restrict__ out, int n8) {
  int i = blockIdx.x * 256 + threadIdx.x;
  if (i >= n8) return;
  const float* p = in + (size_t)i * 8;
  short8 v;
#pragma unroll
  for (int j = 0; j < 8; ++j) v[j] = (short)f2bf(p[j]);
  *(short8*)(out + (size_t)i * 8) = v;
}

// ---------------- RoPE cos/sin table [SEQ][64] ----------------
__global__ void trig_kernel(float* __restrict__ cosT, float* __restrict__ sinT) {
  int i = blockIdx.x * 256 + threadIdx.x;     // SEQ*64 = 131072
  int s = i >> 6, j = i & 63;
  float inv = powf(10000.0f, -2.0f * (float)j / 128.0f);
  float ang = (float)s * inv;
  cosT[i] = cosf(ang);
  sinT[i] = sinf(ang);
}

// ---------------- GEMM: C[M,N] = A[M,K] * B[N,K]^T (bf16 in, fp32 accum) -----
// 128x128 tile, BK=64, 4 waves (2x2), each wave 64x64 = 4x4 fragments of 16x16.
// LDS XOR-swizzled: byte ^= (row&7)<<4  (kills stride-128B ds_read_b128 conflicts)
template<int F32OUT>
__global__ __launch_bounds__(256)
void gemm_bt(const u16* __restrict__ A, const u16* __restrict__ B,
             void* __restrict__ Cv, int M, int N, int K) {
  __shared__ u16 As[128 * 64];
  __shared__ u16 Bs[128 * 64];
  const int T = threadIdx.x;
  const int lane = T & 63, w = T >> 6;
  const int lo = lane & 15, hi = lane >> 4;
  const int wr = w >> 1, wc = w & 1;
  const int bm = blockIdx.y * 128, bn = blockIdx.x * 128;

  f32x4 acc[4][4] = {};

  for (int k0 = 0; k0 < K; k0 += 64) {
    __syncthreads();   // protect LDS from previous iteration's readers
#pragma unroll
    for (int q = 0; q < 4; ++q) {
      int idx = q * 256 + T;
      int row = idx >> 3;
      int col = (idx & 7) << 3;
      int o = ((row << 7) + (col << 1)) ^ ((row & 7) << 4);
      *(short8*)((char*)As + o) = *(const short8*)(A + (size_t)(bm + row) * K + k0 + col);
      *(short8*)((char*)Bs + o) = *(const short8*)(B + (size_t)(bn + row) * K + k0 + col);
    }
    __syncthreads();

    short8 af[4][2], bfr[4][2];
#pragma unroll
    for (int mi = 0; mi < 4; ++mi) {
      int row = wr * 64 + mi * 16 + lo;
#pragma unroll
      for (int c = 0; c < 2; ++c) {
        int o = ((row << 7) + c * 64 + hi * 16) ^ ((row & 7) << 4);
        af[mi][c] = *(short8*)((char*)As + o);
      }
    }
#pragma unroll
    for (int ni = 0; ni < 4; ++ni) {
      int row = wc * 64 + ni * 16 + lo;
#pragma unroll
      for (int c = 0; c < 2; ++c) {
        int o = ((row << 7) + c * 64 + hi * 16) ^ ((row & 7) << 4);
        bfr[ni][c] = *(short8*)((char*)Bs + o);
      }
    }
#pragma unroll
    for (int c = 0; c < 2; ++c)
#pragma unroll
      for (int mi = 0; mi < 4; ++mi)
#pragma unroll
        for (int ni = 0; ni < 4; ++ni)
          acc[mi][ni] = __builtin_amdgcn_mfma_f32_16x16x32_bf16(
              af[mi][c], bfr[ni][c], acc[mi][ni], 0, 0, 0);
  }

  // epilogue: D layout col=lane&15, row=(lane>>4)*4+reg (HW-verified)
#pragma unroll
  for (int mi = 0; mi < 4; ++mi)
#pragma unroll
    for (int ni = 0; ni < 4; ++ni) {
      int row = bm + wr * 64 + mi * 16 + hi * 4;
      int col = bn + wc * 64 + ni * 16 + lo;
#pragma unroll
      for (int r = 0; r < 4; ++r) {
        if (F32OUT)
          ((float*)Cv)[(size_t)(row + r) * N + col] = acc[mi][ni][r];
        else
          ((u16*)Cv)[(size_t)(row + r) * N + col] = f2bf(acc[mi][ni][r]);
      }
    }
}

// ---------------- RoPE in-place on bf16 [NTOK][D_MODEL], 8 elems/thread ------
__global__ void rope_kernel(u16* __restrict__ t, const float* __restrict__ cosT,
                            const float* __restrict__ sinT) {
  int i = blockIdx.x * 256 + threadIdx.x;   // NTOK * 256 groups
  int row = i >> 8;
  int g = i & 255;
  int s = row & (SEQ - 1);
  int col = g << 3;
  int j0 = (col & 127) >> 1;                // pair index within head
  short8 v = *(short8*)(t + (size_t)row * D_MODEL + col);
#pragma unroll
  for (int p = 0; p < 4; ++p) {
    float c  = cosT[s * 64 + j0 + p];
    float sn = sinT[s * 64 + j0 + p];
    float e = bf2f((u16)v[2 * p]), o = bf2f((u16)v[2 * p + 1]);
    v[2 * p]     = (short)f2bf(e * c - o * sn);
    v[2 * p + 1] = (short)f2bf(o * c + e * sn);
  }
  *(short8*)(t + (size_t)row * D_MODEL + col) = v;
}

// ---------------- per-head V transpose: Vb[NTOK][D_MODEL] -> VT[bh][128][SEQ] -
__global__ void vt_kernel(const u16* __restrict__ V, u16* __restrict__ VT) {
  __shared__ u16 tbuf[64][66];   // pad 2 -> stride 33 words, ~2-way max
  int bh = blockIdx.z;
  int b = bh >> 4, h = bh & 15;
  int s0 = blockIdx.x << 6, d0 = blockIdx.y << 6;
  for (int i = threadIdx.x; i < 512; i += 256) {
    int sr = i >> 3, c8 = (i & 7) << 3;
    short8 v = *(const short8*)(V + (size_t)(b * SEQ + s0 + sr) * D_MODEL + h * DKH + d0 + c8);
#pragma unroll
    for (int j = 0; j < 8; ++j) tbuf[sr][c8 + j] = (u16)v[j];
  }
  __syncthreads();
  for (int i = threadIdx.x; i < 512; i += 256) {
    int dr = i >> 3, s8 = (i & 7) << 3;
    short8 v;
#pragma unroll
    for (int j = 0; j < 8; ++j) v[j] = (short)tbuf[s8 + j][dr];
    *(short8*)(VT + ((size_t)bh * DKH + d0 + dr) * SEQ + s0 + s8) = v;
  }
}

// ---------------- causal flash attention ----------------
// block = (q-tile of 64, bh). 4 waves x 16 q-rows. KV tiles of 64.
__global__ __launch_bounds__(256)
void attn_kernel(const u16* __restrict__ Q, const u16* __restrict__ K,
                 const u16* __restrict__ VT, u16* __restrict__ O) {
  __shared__ u16 Ks[64 * 128];     // [kv][d]  swizzled
  __shared__ u16 Vs[128 * 64];     // [d][kv]  swizzled
  __shared__ u16 Ps[4][16 * 64];   // per-wave P, swizzled
  const int T = threadIdx.x, lane = T & 63, w = T >> 6;
  const int lo = lane & 15, hi = lane >> 4;
  const int qt = blockIdx.x, bh = blockIdx.y;
  const int b = bh >> 4, h = bh & 15;
  const int q0 = qt << 6;
  const float scale = 0.08838834764831845f;   // 1/sqrt(128)

  // Q fragments: A-frag row = lane%16 -> q-row q0+16w+lo ; k-slots d = c*32+hi*8+j
  const u16* Qp = Q + ((size_t)(b * SEQ + q0 + w * 16 + lo)) * D_MODEL + h * DKH;
  short8 qf[4];
#pragma unroll
  for (int c = 0; c < 4; ++c) qf[c] = *(const short8*)(Qp + c * 32 + hi * 8);

  f32x4 oacc[8] = {};
  float mrow[4], lrow[4];
#pragma unroll
  for (int r = 0; r < 4; ++r) { mrow[r] = -1e30f; lrow[r] = 0.f; }

  const int ntiles = qt + 1;
  for (int kt = 0; kt < ntiles; ++kt) {
    const int kb = kt << 6;
    __syncthreads();
    // stage K [64][128] and VT [128][64]
#pragma unroll
    for (int qq = 0; qq < 4; ++qq) {
      int idx = qq * 256 + T;
      int kv = idx >> 4, dc = (idx & 15) << 3;
      int o = ((kv << 8) + (dc << 1)) ^ ((kv & 7) << 4);
      *(short8*)((char*)Ks + o) =
          *(const short8*)(K + (size_t)(b * SEQ + kb + kv) * D_MODEL + h * DKH + dc);
      int d = idx >> 3, kc = (idx & 7) << 3;
      int o2 = ((d << 7) + (kc << 1)) ^ ((d & 7) << 4);
      *(short8*)((char*)Vs + o2) =
          *(const short8*)(VT + ((size_t)bh * DKH + d) * SEQ + kb + kc);
    }
    __syncthreads();

    // S = Q K^T   (per wave: 16 q-rows x 64 kv)
    f32x4 sa[4];
#pragma unroll
    for (int g = 0; g < 4; ++g) {
      f32x4 s4 = {0.f, 0.f, 0.f, 0.f};
      int krow = g * 16 + lo;
#pragma unroll
      for (int c = 0; c < 4; ++c) {
        int o = ((krow << 8) + c * 64 + hi * 16) ^ ((krow & 7) << 4);
        short8 kf = *(short8*)((char*)Ks + o);
        s4 = __builtin_amdgcn_mfma_f32_16x16x32_bf16(qf[c], kf, s4, 0, 0, 0);
      }
      sa[g] = s4;
    }

    // scale + causal mask + tile row-max
    const bool diag = (kt == qt);
    float pm[4] = {-1e30f, -1e30f, -1e30f, -1e30f};
#pragma unroll
    for (int g = 0; g < 4; ++g) {
      int kvg = kb + g * 16 + lo;
#pragma unroll
      for (int r = 0; r < 4; ++r) {
        float sv = sa[g][r] * scale;
        if (diag) {
          int qg = q0 + w * 16 + hi * 4 + r;
          if (kvg > qg) sv = -1e30f;
        }
        sa[g][r] = sv;
        pm[r] = fmaxf(pm[r], sv);
      }
    }
#pragma unroll
    for (int mk = 1; mk < 16; mk <<= 1)
#pragma unroll
      for (int r = 0; r < 4; ++r) pm[r] = fmaxf(pm[r], __shfl_xor(pm[r], mk));

    float mnew[4], sc[4], rowsum[4];
#pragma unroll
    for (int r = 0; r < 4; ++r) {
      mnew[r] = fmaxf(mrow[r], pm[r]);
      sc[r] = __expf(mrow[r] - mnew[r]);
      rowsum[r] = 0.f;
    }

    // P = exp(s - mnew); stage per-wave into LDS (S D-layout -> A-frag layout)
#pragma unroll
    for (int g = 0; g < 4; ++g) {
#pragma unroll
      for (int r = 0; r < 4; ++r) {
        float p = __expf(sa[g][r] - mnew[r]);
        rowsum[r] += p;
        int prow = hi * 4 + r;
        int o = ((prow << 7) + ((g * 16 + lo) << 1)) ^ ((prow & 7) << 4);
        *(u16*)((char*)Ps[w] + o) = f2bf(p);
      }
    }
#pragma unroll
    for (int mk = 1; mk < 16; mk <<= 1)
#pragma unroll
      for (int r = 0; r < 4; ++r) rowsum[r] += __shfl_xor(rowsum[r], mk);
#pragma unroll
    for (int r = 0; r < 4; ++r) {
      lrow[r] = lrow[r] * sc[r] + rowsum[r];
      mrow[r] = mnew[r];
    }
#pragma unroll
    for (int g = 0; g < 8; ++g)
#pragma unroll
      for (int r = 0; r < 4; ++r) oacc[g][r] *= sc[r];

    // O += P @ V
#pragma unroll
    for (int c2 = 0; c2 < 2; ++c2) {
      int po = ((lo << 7) + c2 * 64 + hi * 16) ^ ((lo & 7) << 4);
      short8 pf = *(short8*)((char*)Ps[w] + po);
#pragma unroll
      for (int g = 0; g < 8; ++g) {
        int vrow = g * 16 + lo;
        int vo = ((vrow << 7) + c2 * 64 + hi * 16) ^ ((vrow & 7) << 4);
        short8 vf = *(short8*)((char*)Vs + vo);
        oacc[g] = __builtin_amdgcn_mfma_f32_16x16x32_bf16(pf, vf, oacc[g], 0, 0, 0);
      }
    }
  }

  // epilogue: divide by l, store bf16
  u16* Op = O + ((size_t)(b * SEQ + q0 + w * 16 + hi * 4)) * D_MODEL + h * DKH;
#pragma unroll
  for (int g = 0; g < 8; ++g)
#pragma unroll
    for (int r = 0; r < 4; ++r) {
      float ov = oacc[g][r] / lrow[r];
      Op[(size_t)r * D_MODEL + g * 16 + lo] = f2bf(ov);
    }
}

extern "C" void kernel_launch(void* const* d_in, const int* in_sizes, int n_in,
                              void* d_out, int out_size, void* d_ws, size_t ws_size,
                              hipStream_t stream) {
  const float* x  = (const float*)d_in[0];
  const float* wq = (const float*)d_in[1];
  const float* wk = (const float*)d_in[2];
  const float* wv = (const float*)d_in[3];
  const float* wo = (const float*)d_in[4];
  float* out = (float*)d_out;

  const size_t TOKB = (size_t)NTOK * D_MODEL * 2;       // 33.5 MB
  const size_t WB   = (size_t)D_MODEL * D_MODEL * 2;    // 8.4 MB
  char* p = (char*)d_ws;
  u16* xb  = (u16*)p; p += TOKB;
  u16* wqb = (u16*)p; p += WB;
  u16* wkb = (u16*)p; p += WB;
  u16* wvb = (u16*)p; p += WB;
  u16* wob = (u16*)p; p += WB;
  u16* Qb  = (u16*)p; p += TOKB;
  u16* Kb  = (u16*)p; p += TOKB;
  u16* Vb  = (u16*)p; p += TOKB;
  u16* VTb = (u16*)p; p += TOKB;
  u16* Ob  = (u16*)p; p += TOKB;
  float* cosT = (float*)p; p += (size_t)SEQ * 64 * 4;
  float* sinT = (float*)p; p += (size_t)SEQ * 64 * 4;

  // bf16 conversions
  cvt_kernel<<<8192, 256, 0, stream>>>(x,  xb,  2097152);
  cvt_kernel<<<2048, 256, 0, stream>>>(wq, wqb, 524288);
  cvt_kernel<<<2048, 256, 0, stream>>>(wk, wkb, 524288);
  cvt_kernel<<<2048, 256, 0, stream>>>(wv, wvb, 524288);
  cvt_kernel<<<2048, 256, 0, stream>>>(wo, wob, 524288);
  trig_kernel<<<512, 256, 0, stream>>>(cosT, sinT);

  dim3 gg(16, 64);   // (N/128, M/128)
  gemm_bt<0><<<gg, 256, 0, stream>>>(xb, wqb, Qb, NTOK, D_MODEL, D_MODEL);
  gemm_bt<0><<<gg, 256, 0, stream>>>(xb, wkb, Kb, NTOK, D_MODEL, D_MODEL);
  gemm_bt<0><<<gg, 256, 0, stream>>>(xb, wvb, Vb, NTOK, D_MODEL, D_MODEL);

  rope_kernel<<<8192, 256, 0, stream>>>(Qb, cosT, sinT);
  rope_kernel<<<8192, 256, 0, stream>>>(Kb, cosT, sinT);

  vt_kernel<<<dim3(32, 2, 64), 256, 0, stream>>>(Vb, VTb);

  attn_kernel<<<dim3(32, 64), 256, 0, stream>>>(Qb, Kb, VTb, Ob);

  gemm_bt<1><<<gg, 256, 0, stream>>>(Ob, wob, out, NTOK, D_MODEL, D_MODEL);
}

// Round 2
// 620.281 us; speedup vs baseline: 1.2885x; 1.2885x over previous
//
#include <hip/hip_runtime.h>
#include <hip/hip_bf16.h>
#include <cstdint>
#include <cstddef>

typedef unsigned short u16;
typedef __attribute__((ext_vector_type(8))) short short8;   // 8 x bf16 (4 VGPRs) MFMA frag
typedef __attribute__((ext_vector_type(4))) float f32x4;    // MFMA accum

#define D_MODEL 2048
#define SEQ     2048
#define BATCH   4
#define NHEADS  16
#define DKH     128
#define NTOK    (BATCH*SEQ)   // 8192

__device__ inline float bf2f(u16 u) {
  union { float f; unsigned int i; } x; x.i = ((unsigned int)u) << 16; return x.f;
}
__device__ inline u16 f2bf(float f) {
  union { float f; unsigned int i; } x; x.f = f;
  return (u16)((x.i + 0x7FFFu + ((x.i >> 16) & 1u)) >> 16);   // RNE
}

// ---------------- fp32 -> bf16 convert, 8 elems/thread ----------------
__global__ void cvt_kernel(const float* __restrict__ in, u16* __restrict__ out, int n8) {
  int i = blockIdx.x * 256 + threadIdx.x;
  if (i >= n8) return;
  const float* p = in + (size_t)i * 8;
  short8 v;
#pragma unroll
  for (int j = 0; j < 8; ++j) v[j] = (short)f2bf(p[j]);
  *(short8*)(out + (size_t)i * 8) = v;
}

// ---------------- RoPE cos/sin table [SEQ][64] ----------------
__global__ void trig_kernel(float* __restrict__ cosT, float* __restrict__ sinT) {
  int i = blockIdx.x * 256 + threadIdx.x;     // SEQ*64 = 131072
  int s = i >> 6, j = i & 63;
  float inv = powf(10000.0f, -2.0f * (float)j / 128.0f);
  float ang = (float)s * inv;
  cosT[i] = cosf(ang);
  sinT[i] = sinf(ang);
}

// ---------------- GEMM: C[M,N] = A[M,K] * B[N,K]^T (bf16 in, fp32 accum) -----
// 128x128 tile, BK=64, 4 waves (2x2), each wave 64x64 = 4x4 fragments of 16x16.
// LDS XOR-swizzled: byte ^= (row&7)<<4  (kills stride-128B ds_read_b128 conflicts)
template<int F32OUT>
__global__ __launch_bounds__(256)
void gemm_bt(const u16* __restrict__ A, const u16* __restrict__ B,
             void* __restrict__ Cv, int M, int N, int K) {
  __shared__ u16 As[128 * 64];
  __shared__ u16 Bs[128 * 64];
  const int T = threadIdx.x;
  const int lane = T & 63, w = T >> 6;
  const int lo = lane & 15, hi = lane >> 4;
  const int wr = w >> 1, wc = w & 1;
  const int bm = blockIdx.y * 128, bn = blockIdx.x * 128;

  f32x4 acc[4][4] = {};

  for (int k0 = 0; k0 < K; k0 += 64) {
    __syncthreads();   // protect LDS from previous iteration's readers
#pragma unroll
    for (int q = 0; q < 4; ++q) {
      int idx = q * 256 + T;
      int row = idx >> 3;
      int col = (idx & 7) << 3;
      int o = ((row << 7) + (col << 1)) ^ ((row & 7) << 4);
      *(short8*)((char*)As + o) = *(const short8*)(A + (size_t)(bm + row) * K + k0 + col);
      *(short8*)((char*)Bs + o) = *(const short8*)(B + (size_t)(bn + row) * K + k0 + col);
    }
    __syncthreads();

    short8 af[4][2], bfr[4][2];
#pragma unroll
    for (int mi = 0; mi < 4; ++mi) {
      int row = wr * 64 + mi * 16 + lo;
#pragma unroll
      for (int c = 0; c < 2; ++c) {
        int o = ((row << 7) + c * 64 + hi * 16) ^ ((row & 7) << 4);
        af[mi][c] = *(short8*)((char*)As + o);
      }
    }
#pragma unroll
    for (int ni = 0; ni < 4; ++ni) {
      int row = wc * 64 + ni * 16 + lo;
#pragma unroll
      for (int c = 0; c < 2; ++c) {
        int o = ((row << 7) + c * 64 + hi * 16) ^ ((row & 7) << 4);
        bfr[ni][c] = *(short8*)((char*)Bs + o);
      }
    }
#pragma unroll
    for (int c = 0; c < 2; ++c)
#pragma unroll
      for (int mi = 0; mi < 4; ++mi)
#pragma unroll
        for (int ni = 0; ni < 4; ++ni)
          acc[mi][ni] = __builtin_amdgcn_mfma_f32_16x16x32_bf16(
              af[mi][c], bfr[ni][c], acc[mi][ni], 0, 0, 0);
  }

  // epilogue: D layout col=lane&15, row=(lane>>4)*4+reg (HW-verified)
#pragma unroll
  for (int mi = 0; mi < 4; ++mi)
#pragma unroll
    for (int ni = 0; ni < 4; ++ni) {
      int row = bm + wr * 64 + mi * 16 + hi * 4;
      int col = bn + wc * 64 + ni * 16 + lo;
#pragma unroll
      for (int r = 0; r < 4; ++r) {
        if (F32OUT)
          ((float*)Cv)[(size_t)(row + r) * N + col] = acc[mi][ni][r];
        else
          ((u16*)Cv)[(size_t)(row + r) * N + col] = f2bf(acc[mi][ni][r]);
      }
    }
}

// ---------------- RoPE in-place on bf16 [NTOK][D_MODEL], 8 elems/thread ------
// premul: extra scalar folded into the output (Q gets 1/sqrt(dk)*log2(e), K gets 1)
__global__ void rope_kernel(u16* __restrict__ t, const float* __restrict__ cosT,
                            const float* __restrict__ sinT, float premul) {
  int i = blockIdx.x * 256 + threadIdx.x;   // NTOK * 256 groups
  int row = i >> 8;
  int g = i & 255;
  int s = row & (SEQ - 1);
  int col = g << 3;
  int j0 = (col & 127) >> 1;                // pair index within head
  short8 v = *(short8*)(t + (size_t)row * D_MODEL + col);
#pragma unroll
  for (int p = 0; p < 4; ++p) {
    float c  = cosT[s * 64 + j0 + p];
    float sn = sinT[s * 64 + j0 + p];
    float e = bf2f((u16)v[2 * p]), o = bf2f((u16)v[2 * p + 1]);
    v[2 * p]     = (short)f2bf((e * c - o * sn) * premul);
    v[2 * p + 1] = (short)f2bf((o * c + e * sn) * premul);
  }
  *(short8*)(t + (size_t)row * D_MODEL + col) = v;
}

// ---------------- per-head V transpose: Vb[NTOK][D_MODEL] -> VT[bh][128][SEQ] -
__global__ void vt_kernel(const u16* __restrict__ V, u16* __restrict__ VT) {
  __shared__ u16 tbuf[64][66];   // pad 2 -> ~2-way max
  int bh = blockIdx.z;
  int b = bh >> 4, h = bh & 15;
  int s0 = blockIdx.x << 6, d0 = blockIdx.y << 6;
  for (int i = threadIdx.x; i < 512; i += 256) {
    int sr = i >> 3, c8 = (i & 7) << 3;
    short8 v = *(const short8*)(V + (size_t)(b * SEQ + s0 + sr) * D_MODEL + h * DKH + d0 + c8);
#pragma unroll
    for (int j = 0; j < 8; ++j) tbuf[sr][c8 + j] = (u16)v[j];
  }
  __syncthreads();
  for (int i = threadIdx.x; i < 512; i += 256) {
    int dr = i >> 3, s8 = (i & 7) << 3;
    short8 v;
#pragma unroll
    for (int j = 0; j < 8; ++j) v[j] = (short)tbuf[s8 + j][dr];
    *(short8*)(VT + ((size_t)bh * DKH + d0 + dr) * SEQ + s0 + s8) = v;
  }
}

// ---------------- causal flash attention ----------------
// Scores arrive pre-scaled by 1/sqrt(dk)*log2(e) (folded into Q's RoPE), so
// softmax runs natively in exp2 domain. Defer-max threshold = 8 (p <= 2^8).
__device__ __forceinline__ void attn_qtile(
    int qt, int b, int h, int bh,
    const u16* __restrict__ Q, const u16* __restrict__ K,
    const u16* __restrict__ VT, u16* __restrict__ O,
    u16* Ks, u16* Vs, u16* Pw)
{
  const int T = threadIdx.x, lane = T & 63, w = T >> 6;
  const int lo = lane & 15, hi = lane >> 4;
  const int q0 = qt << 6;

  // Q fragments: A-frag row = lane%16 -> q-row q0+16w+lo ; k-slots d = c*32+hi*8+j
  const u16* Qp = Q + ((size_t)(b * SEQ + q0 + w * 16 + lo)) * D_MODEL + h * DKH;
  short8 qf[4];
#pragma unroll
  for (int c = 0; c < 4; ++c) qf[c] = *(const short8*)(Qp + c * 32 + hi * 8);

  f32x4 oacc[8] = {};
  float mrow[4], lrow[4];
#pragma unroll
  for (int r = 0; r < 4; ++r) { mrow[r] = -1e30f; lrow[r] = 0.f; }

  for (int kt = 0; kt <= qt; ++kt) {
    const int kb = kt << 6;
    __syncthreads();
    // stage K [64][128] and VT [128][64], both XOR-swizzled
#pragma unroll
    for (int qq = 0; qq < 4; ++qq) {
      int idx = qq * 256 + T;
      int kv = idx >> 4, dc = (idx & 15) << 3;
      int o = ((kv << 8) + (dc << 1)) ^ ((kv & 7) << 4);
      *(short8*)((char*)Ks + o) =
          *(const short8*)(K + (size_t)(b * SEQ + kb + kv) * D_MODEL + h * DKH + dc);
      int d = idx >> 3, kc = (idx & 7) << 3;
      int o2 = ((d << 7) + (kc << 1)) ^ ((d & 7) << 4);
      *(short8*)((char*)Vs + o2) =
          *(const short8*)(VT + ((size_t)bh * DKH + d) * SEQ + kb + kc);
    }
    __syncthreads();

    // S = Q K^T   (per wave: 16 q-rows x 64 kv) -- already in exp2 domain
    f32x4 sa[4];
    __builtin_amdgcn_s_setprio(1);
#pragma unroll
    for (int g = 0; g < 4; ++g) {
      f32x4 s4 = {0.f, 0.f, 0.f, 0.f};
      int krow = g * 16 + lo;
#pragma unroll
      for (int c = 0; c < 4; ++c) {
        int o = ((krow << 8) + c * 64 + hi * 16) ^ ((krow & 7) << 4);
        short8 kf = *(short8*)((char*)Ks + o);
        s4 = __builtin_amdgcn_mfma_f32_16x16x32_bf16(qf[c], kf, s4, 0, 0, 0);
      }
      sa[g] = s4;
    }
    __builtin_amdgcn_s_setprio(0);

    // causal mask + tile row-max
    const bool diag = (kt == qt);
    float pm[4] = {-1e30f, -1e30f, -1e30f, -1e30f};
#pragma unroll
    for (int g = 0; g < 4; ++g) {
      int kvg = kb + g * 16 + lo;
#pragma unroll
      for (int r = 0; r < 4; ++r) {
        float sv = sa[g][r];
        if (diag) {
          int qg = q0 + w * 16 + hi * 4 + r;
          if (kvg > qg) sv = -1e30f;
        }
        sa[g][r] = sv;
        pm[r] = fmaxf(pm[r], sv);
      }
    }
#pragma unroll
    for (int mk = 1; mk < 16; mk <<= 1)
#pragma unroll
      for (int r = 0; r < 4; ++r) pm[r] = fmaxf(pm[r], __shfl_xor(pm[r], mk));

    // defer-max (T13): only rescale when the tile max grew by > 8 (exp2 dom.)
    int pred = 1;
#pragma unroll
    for (int r = 0; r < 4; ++r) pred &= (pm[r] <= mrow[r] + 8.0f);
    if (!__all(pred)) {
#pragma unroll
      for (int r = 0; r < 4; ++r) {
        float mnew = fmaxf(mrow[r], pm[r]);
        float sc = __builtin_amdgcn_exp2f(mrow[r] - mnew);
        lrow[r] *= sc;
        mrow[r] = mnew;
#pragma unroll
        for (int g = 0; g < 8; ++g) oacc[g][r] *= sc;
      }
    }

    // P = exp2(s - m); stage per-wave into LDS (S D-layout -> A-frag layout)
    float rowsum[4] = {0.f, 0.f, 0.f, 0.f};
#pragma unroll
    for (int g = 0; g < 4; ++g) {
#pragma unroll
      for (int r = 0; r < 4; ++r) {
        float p = __builtin_amdgcn_exp2f(sa[g][r] - mrow[r]);
        rowsum[r] += p;
        int prow = hi * 4 + r;
        int o = ((prow << 7) + ((g * 16 + lo) << 1)) ^ ((prow & 7) << 4);
        *(u16*)((char*)Pw + o) = f2bf(p);
      }
    }
#pragma unroll
    for (int mk = 1; mk < 16; mk <<= 1)
#pragma unroll
      for (int r = 0; r < 4; ++r) rowsum[r] += __shfl_xor(rowsum[r], mk);
#pragma unroll
    for (int r = 0; r < 4; ++r) lrow[r] += rowsum[r];

    // O += P @ V
    __builtin_amdgcn_s_setprio(1);
#pragma unroll
    for (int c2 = 0; c2 < 2; ++c2) {
      int po = ((lo << 7) + c2 * 64 + hi * 16) ^ ((lo & 7) << 4);
      short8 pf = *(short8*)((char*)Pw + po);
#pragma unroll
      for (int g = 0; g < 8; ++g) {
        int vrow = g * 16 + lo;
        int vo = ((vrow << 7) + c2 * 64 + hi * 16) ^ ((vrow & 7) << 4);
        short8 vf = *(short8*)((char*)Vs + vo);
        oacc[g] = __builtin_amdgcn_mfma_f32_16x16x32_bf16(pf, vf, oacc[g], 0, 0, 0);
      }
    }
    __builtin_amdgcn_s_setprio(0);
  }

  // epilogue: divide by l, store bf16
  u16* Op = O + ((size_t)(b * SEQ + q0 + w * 16 + hi * 4)) * D_MODEL + h * DKH;
#pragma unroll
  for (int g = 0; g < 8; ++g)
#pragma unroll
    for (int r = 0; r < 4; ++r) {
      float ov = oacc[g][r] / lrow[r];
      Op[(size_t)r * D_MODEL + g * 16 + lo] = f2bf(ov);
    }
}

// block = one (bh, q-tile-pair): processes q-tiles (31-pair) and (pair) so every
// block does exactly 33 KV-tiles -> uniform work, 1024 blocks = 4/CU resident.
__global__ __launch_bounds__(256)
void attn_kernel(const u16* __restrict__ Q, const u16* __restrict__ K,
                 const u16* __restrict__ VT, u16* __restrict__ O) {
  __shared__ u16 Ks[64 * 128];
  __shared__ u16 Vs[128 * 64];
  __shared__ u16 Ps[4 * 16 * 64];
  const int wg = blockIdx.x;
  const int xcd = wg & 7, idx = wg >> 3;
  const int bh = xcd * 8 + (idx >> 4);    // 8 consecutive bh per XCD chunk
  const int pair = idx & 15;
  const int b = bh >> 4, h = bh & 15;
  u16* Pw = Ps + (threadIdx.x >> 6) * 1024;
#pragma unroll 1
  for (int side = 0; side < 2; ++side) {
    const int qt = side ? pair : 31 - pair;
    attn_qtile(qt, b, h, bh, Q, K, VT, O, Ks, Vs, Pw);
  }
}

extern "C" void kernel_launch(void* const* d_in, const int* in_sizes, int n_in,
                              void* d_out, int out_size, void* d_ws, size_t ws_size,
                              hipStream_t stream) {
  const float* x  = (const float*)d_in[0];
  const float* wq = (const float*)d_in[1];
  const float* wk = (const float*)d_in[2];
  const float* wv = (const float*)d_in[3];
  const float* wo = (const float*)d_in[4];
  float* out = (float*)d_out;

  const size_t TOKB = (size_t)NTOK * D_MODEL * 2;       // 33.5 MB
  const size_t WB   = (size_t)D_MODEL * D_MODEL * 2;    // 8.4 MB
  char* p = (char*)d_ws;
  u16* xb  = (u16*)p; p += TOKB;
  u16* wqb = (u16*)p; p += WB;
  u16* wkb = (u16*)p; p += WB;
  u16* wvb = (u16*)p; p += WB;
  u16* wob = (u16*)p; p += WB;
  u16* Qb  = (u16*)p; p += TOKB;
  u16* Kb  = (u16*)p; p += TOKB;
  u16* Vb  = (u16*)p; p += TOKB;
  u16* VTb = (u16*)p; p += TOKB;
  u16* Ob  = (u16*)p; p += TOKB;
  float* cosT = (float*)p; p += (size_t)SEQ * 64 * 4;
  float* sinT = (float*)p; p += (size_t)SEQ * 64 * 4;

  // bf16 conversions
  cvt_kernel<<<8192, 256, 0, stream>>>(x,  xb,  2097152);
  cvt_kernel<<<2048, 256, 0, stream>>>(wq, wqb, 524288);
  cvt_kernel<<<2048, 256, 0, stream>>>(wk, wkb, 524288);
  cvt_kernel<<<2048, 256, 0, stream>>>(wv, wvb, 524288);
  cvt_kernel<<<2048, 256, 0, stream>>>(wo, wob, 524288);
  trig_kernel<<<512, 256, 0, stream>>>(cosT, sinT);

  dim3 gg(16, 64);   // (N/128, M/128)
  gemm_bt<0><<<gg, 256, 0, stream>>>(xb, wqb, Qb, NTOK, D_MODEL, D_MODEL);
  gemm_bt<0><<<gg, 256, 0, stream>>>(xb, wkb, Kb, NTOK, D_MODEL, D_MODEL);
  gemm_bt<0><<<gg, 256, 0, stream>>>(xb, wvb, Vb, NTOK, D_MODEL, D_MODEL);

  // Q gets 1/sqrt(dk) * log2(e) folded in -> attention softmax in exp2 domain
  rope_kernel<<<8192, 256, 0, stream>>>(Qb, cosT, sinT,
      0.08838834764831845f * 1.4426950408889634f);
  rope_kernel<<<8192, 256, 0, stream>>>(Kb, cosT, sinT, 1.0f);

  vt_kernel<<<dim3(32, 2, 64), 256, 0, stream>>>(Vb, VTb);

  attn_kernel<<<1024, 256, 0, stream>>>(Qb, Kb, VTb, Ob);

  gemm_bt<1><<<gg, 256, 0, stream>>>(Ob, wob, out, NTOK, D_MODEL, D_MODEL);
}